// Round 5
// baseline (568.097 us; speedup 1.0000x reference)
//
#include <hip/hip_runtime.h>
#include <hip/hip_bf16.h>

// B=128, T=512, I=128, H=256, O=1 (fp32 in/out)
// FULLY FUSED single kernel (R5 = R4 fusion, 4 waves x mt=4):
//   v = S*(bias + W_ih·x_t + W_hh·h_t) accumulated in MFMA (S = 2*log2e),
//   h = 1 - 2*rcp(exp2(v)+1)   (exactly tanh)
// R5 change: 8 waves x 2mt -> 4 waves x 4mt. The h/x LDS fragments are
// identical across waves (read offsets are lane-only), so wave count directly
// multiplies redundant DS traffic: 96 -> 48 b128 reads per CU-step (~1300 ->
// ~700 cy on the DS pipe, the dominant consumer per R4 counters). W frags
// stay register-resident (~192 VGPR steady, 1 wave/SIMD).
// Pipeline per step t (one barrier per step):
//   global-load x_{t+3} (reg) | ds_write x_{t+2} (bf16, swizzled b128) |
//   ds_read h_t (8) + x_{t+1} (4) frags | 32 h-MFMA + 16 x-MFMA (seeded bias') |
//   tanh epilogue (16 elem) -> ds_write h_{t+1} | BAR

#define B_ 128
#define T_ 512
#define I_ 128
#define H_ 256
#define SCALE 2.8853900817779268f   // 2*log2(e)

typedef __attribute__((ext_vector_type(8))) short short8;
typedef __attribute__((ext_vector_type(4))) float floatx4;

__device__ __forceinline__ short8 pack8(float4 lo, float4 hi) {
    __hip_bfloat162 p0 = __float22bfloat162_rn(float2{lo.x, lo.y});
    __hip_bfloat162 p1 = __float22bfloat162_rn(float2{lo.z, lo.w});
    __hip_bfloat162 p2 = __float22bfloat162_rn(float2{hi.x, hi.y});
    __hip_bfloat162 p3 = __float22bfloat162_rn(float2{hi.z, hi.w});
    int4 i;
    i.x = *(int*)&p0; i.y = *(int*)&p1; i.z = *(int*)&p2; i.w = *(int*)&p3;
    return *(short8*)&i;
}
__device__ __forceinline__ short8 pack8s(float4 lo, float4 hi, float s) {
    lo.x *= s; lo.y *= s; lo.z *= s; lo.w *= s;
    hi.x *= s; hi.y *= s; hi.z *= s; hi.w *= s;
    return pack8(lo, hi);
}
// tanh(z) where v = 2*log2e*z is the prescaled MFMA result.
// Builtins (not asm) so MFMA->VALU hazards are compiler-handled (R3 lesson).
__device__ __forceinline__ float tanh_s(float v) {
    float e = __builtin_amdgcn_exp2f(v);          // 2^v = exp(2z)
    float r = __builtin_amdgcn_rcpf(e + 1.0f);
    return __builtin_fmaf(-2.0f, r, 1.0f);        // 1 - 2/(e+1)
}

__global__ __launch_bounds__(256, 1)
void rnn_fused(const float* __restrict__ x, const float* __restrict__ W_ih,
               const float* __restrict__ W_hh, const float* __restrict__ b_ih,
               const float* __restrict__ b_hh, const float* __restrict__ W_fc,
               const float* __restrict__ b_fc, float* __restrict__ out) {
    __shared__ __align__(16) short hbuf[2][16][256];   // h_t bf16, 16B-XOR swizzled
    __shared__ __align__(16) short xbuf[2][16][128];   // x_t bf16, 16B-XOR swizzled
    const int tid  = threadIdx.x;
    const int wave = tid >> 6, lane = tid & 63;
    const int l15  = lane & 15, quad = lane >> 4;
    const int b0   = blockIdx.x * 16;
    const int n0   = wave * 64;
    const int swz  = l15 & 7;

    // resident W_hh' fragments (prescaled): 4 mt x 8 kq
    short8 wfrag[4][8];
#pragma unroll
    for (int mt = 0; mt < 4; ++mt)
#pragma unroll
        for (int kq = 0; kq < 8; ++kq) {
            const float* p = W_hh + (long)(n0 + mt * 16 + l15) * H_ + kq * 32 + quad * 8;
            wfrag[mt][kq] = pack8s(*(const float4*)p, *(const float4*)(p + 4), SCALE);
        }
    // resident W_ih' fragments (prescaled): 4 mt x 4 kq
    short8 wih[4][4];
#pragma unroll
    for (int mt = 0; mt < 4; ++mt)
#pragma unroll
        for (int kq = 0; kq < 4; ++kq) {
            const float* p = W_ih + (long)(n0 + mt * 16 + l15) * I_ + kq * 32 + quad * 8;
            wih[mt][kq] = pack8s(*(const float4*)p, *(const float4*)(p + 4), SCALE);
        }
    // prescaled bias per output element: n = n0 + mt*16 + quad*4 + r
    floatx4 bias2[4];
#pragma unroll
    for (int mt = 0; mt < 4; ++mt)
#pragma unroll
        for (int r = 0; r < 4; ++r) {
            int n = n0 + mt * 16 + quad * 4 + r;
            bias2[mt][r] = SCALE * (b_ih[n] + b_hh[n]);
        }

    // zero hbuf[0] (h_0 = 0)
    {
        int* hz = (int*)&hbuf[0][0][0];
#pragma unroll
        for (int i = tid; i < 16 * 256 / 2; i += 256) hz[i] = 0;
    }

    // x staging: thread (sb=batch, sj8=8-float chunk); 16B-granule swizzle sj8^(sb&7)
    const int sb = tid >> 4, sj8 = tid & 15;
    const float* xsrc = x + (long)(b0 + sb) * T_ * I_ + sj8 * 8;
    const int xwoff = sb * 128 + ((sj8 ^ (sb & 7)) << 3);
    {   // stage x_1 -> xbuf[1]
        float4 lo = *(const float4*)(xsrc + I_);
        float4 hi = *(const float4*)(xsrc + I_ + 4);
        *(short8*)(&xbuf[1][0][0] + xwoff) = pack8(lo, hi);
    }
    float4 xhA0 = *(const float4*)(xsrc + 2 * I_);       // x_2, written during step 0
    float4 xhA1 = *(const float4*)(xsrc + 2 * I_ + 4);
    float4 xhB0, xhB1;

    // LDS read offsets (shorts)
    int roff[8];
#pragma unroll
    for (int kq = 0; kq < 8; ++kq)
        roff[kq] = l15 * 256 + (((quad + 4 * kq) ^ swz) << 3);
    int xroff[4];
#pragma unroll
    for (int kq = 0; kq < 4; ++kq)
        xroff[kq] = l15 * 128 + (((kq * 4 + quad) ^ swz) << 3);
    int woff[4];
#pragma unroll
    for (int mt = 0; mt < 4; ++mt) {
        int c = wave * 8 + mt * 2 + (quad >> 1);
        woff[mt] = l15 * 256 + ((c ^ swz) << 3) + (quad & 1) * 4;
    }

    // prolog: aA = bias' + W_ih'·x_0 (x_0 direct from global)
    floatx4 aA[4], aB[4];
    {
        short8 xf[4];
#pragma unroll
        for (int kq = 0; kq < 4; ++kq) {
            const float* p = x + (long)(b0 + l15) * T_ * I_ + kq * 32 + quad * 8;
            xf[kq] = pack8(*(const float4*)p, *(const float4*)(p + 4));
        }
#pragma unroll
        for (int mt = 0; mt < 4; ++mt) aA[mt] = bias2[mt];
#pragma unroll
        for (int kq = 0; kq < 4; ++kq)
#pragma unroll
            for (int mt = 0; mt < 4; ++mt)
                aA[mt] = __builtin_amdgcn_mfma_f32_16x16x32_bf16(
                    wih[mt][kq], xf[kq], aA[mt], 0, 0, 0);
    }
    __syncthreads();   // staging + zero visible before step 0

    const short* hb0r = &hbuf[0][0][0]; short* hb0w = &hbuf[0][0][0];
    const short* hb1r = &hbuf[1][0][0]; short* hb1w = &hbuf[1][0][0];
    const short* xb0r = &xbuf[0][0][0]; short* xb0w = &xbuf[0][0][0];
    const short* xb1r = &xbuf[1][0][0]; short* xb1w = &xbuf[1][0][0];

#define BAR() asm volatile("s_waitcnt lgkmcnt(0)\n\ts_barrier" ::: "memory")

#define STEP(HR, HW, XR, XW, ACUR, ANXT, XH0, XH1, XN0, XN1, TLD)               \
    {                                                                           \
        XN0 = *(const float4*)(xsrc + (long)(TLD) * I_);                        \
        XN1 = *(const float4*)(xsrc + (long)(TLD) * I_ + 4);                    \
        *(short8*)((XW) + xwoff) = pack8(XH0, XH1);                             \
        short8 hfrag[8];                                                        \
        _Pragma("unroll")                                                       \
        for (int kq = 0; kq < 8; ++kq)                                          \
            hfrag[kq] = *(const short8*)((HR) + roff[kq]);                      \
        short8 xfrag[4];                                                        \
        _Pragma("unroll")                                                       \
        for (int kq = 0; kq < 4; ++kq)                                          \
            xfrag[kq] = *(const short8*)((XR) + xroff[kq]);                     \
        _Pragma("unroll")                                                       \
        for (int kq = 0; kq < 8; ++kq)                                          \
            _Pragma("unroll")                                                   \
            for (int mt = 0; mt < 4; ++mt)                                      \
                ACUR[mt] = __builtin_amdgcn_mfma_f32_16x16x32_bf16(             \
                    wfrag[mt][kq], hfrag[kq], ACUR[mt], 0, 0, 0);               \
        _Pragma("unroll")                                                       \
        for (int mt = 0; mt < 4; ++mt) ANXT[mt] = bias2[mt];                    \
        _Pragma("unroll")                                                       \
        for (int kq = 0; kq < 4; ++kq)                                          \
            _Pragma("unroll")                                                   \
            for (int mt = 0; mt < 4; ++mt)                                      \
                ANXT[mt] = __builtin_amdgcn_mfma_f32_16x16x32_bf16(             \
                    wih[mt][kq], xfrag[kq], ANXT[mt], 0, 0, 0);                 \
        _Pragma("unroll")                                                       \
        for (int mt = 0; mt < 4; ++mt) {                                        \
            float r0 = tanh_s(ACUR[mt][0]);                                     \
            float r1 = tanh_s(ACUR[mt][1]);                                     \
            float r2 = tanh_s(ACUR[mt][2]);                                     \
            float r3 = tanh_s(ACUR[mt][3]);                                     \
            __hip_bfloat162 q01 = __float22bfloat162_rn(float2{r0, r1});        \
            __hip_bfloat162 q23 = __float22bfloat162_rn(float2{r2, r3});        \
            int2 wv; wv.x = *(int*)&q01; wv.y = *(int*)&q23;                    \
            *(int2*)((HW) + woff[mt]) = wv;                                     \
        }                                                                       \
        BAR();                                                                  \
    }

#pragma unroll 1
    for (int t = 0; t < T_; t += 2) {
        const int tl0 = (t + 3 < T_) ? t + 3 : T_ - 1;
        const int tl1 = (t + 4 < T_) ? t + 4 : T_ - 1;
        STEP(hb0r, hb1w, xb1r, xb0w, aA, aB, xhA0, xhA1, xhB0, xhB1, tl0);  // even t
        STEP(hb1r, hb0w, xb0r, xb1w, aB, aA, xhB0, xhB1, xhA0, xhA1, tl1);  // odd t
    }
#undef STEP
#undef BAR

    // head: out[b] = sigmoid(b_fc + sum_n h_T[b][n] * W_fc[n]); h_T in hbuf[0] (swizzled)
    {
        const int bl = tid >> 4, seg = tid & 15;
        const int bswz = bl & 7;
        float p = 0.0f;
#pragma unroll
        for (int half = 0; half < 2; ++half) {
            const int c = 2 * seg + half;
            const short* hr = &hbuf[0][0][0] + bl * 256 + ((c ^ bswz) << 3);
#pragma unroll
            for (int i = 0; i < 8; ++i) {
                __hip_bfloat16 hv = *(const __hip_bfloat16*)(hr + i);
                p += __bfloat162float(hv) * W_fc[c * 8 + i];
            }
        }
#pragma unroll
        for (int off = 1; off < 16; off <<= 1) p += __shfl_xor(p, off);
        if (seg == 0) out[b0 + bl] = 1.0f / (1.0f + __expf(-(p + b_fc[0])));
    }
}

extern "C" void kernel_launch(void* const* d_in, const int* in_sizes, int n_in,
                              void* d_out, int out_size, void* d_ws, size_t ws_size,
                              hipStream_t stream) {
    const float* x    = (const float*)d_in[0];
    const float* W_ih = (const float*)d_in[1];
    const float* W_hh = (const float*)d_in[2];
    const float* b_ih = (const float*)d_in[3];
    const float* b_hh = (const float*)d_in[4];
    const float* W_fc = (const float*)d_in[5];
    const float* b_fc = (const float*)d_in[6];
    float* out = (float*)d_out;
    (void)d_ws; (void)ws_size;   // workspace not needed

    rnn_fused<<<B_ / 16, 256, 0, stream>>>(x, W_ih, W_hh, b_ih, b_hh, W_fc, b_fc, out);
}

// Round 6
// 414.820 us; speedup vs baseline: 1.3695x; 1.3695x over previous
//
#include <hip/hip_runtime.h>
#include <hip/hip_bf16.h>

// B=128, T=512, I=128, H=256, O=1 (fp32 in/out)
// FULLY FUSED single kernel (R6 = R4 config + scheduling fixes):
//   v = S*(bias + W_ih·x_t + W_hh·h_t) accumulated in MFMA (S = 2*log2e),
//   h = 1 - 2*rcp(exp2(v)+1)   (exactly tanh)
// R6 changes vs R4 (R5's 4-wave config regressed: latency-bound at 1 wave/SIMD):
//   * h-MFMA chain split 8 -> 4+4 (aC carries seeded acc, aZ zero-seeded; merged
//     by 8 v_add before tanh) -> 4 independent depth-4 chains per wave
//   * step reorder: glb x load | h-frag reads | 16 h-MFMA | x-frag reads +
//     x stage write (fills DS idle) | merge+tanh+h-write (critical path) |
//     8 x-MFMA last (needed only after next barrier, overlaps epilogue VALU)
// 8 waves x mt=2, 2 waves/SIMD, one barrier per step.

#define B_ 128
#define T_ 512
#define I_ 128
#define H_ 256
#define SCALE 2.8853900817779268f   // 2*log2(e)

typedef __attribute__((ext_vector_type(8))) short short8;
typedef __attribute__((ext_vector_type(4))) float floatx4;

__device__ __forceinline__ short8 pack8(float4 lo, float4 hi) {
    __hip_bfloat162 p0 = __float22bfloat162_rn(float2{lo.x, lo.y});
    __hip_bfloat162 p1 = __float22bfloat162_rn(float2{lo.z, lo.w});
    __hip_bfloat162 p2 = __float22bfloat162_rn(float2{hi.x, hi.y});
    __hip_bfloat162 p3 = __float22bfloat162_rn(float2{hi.z, hi.w});
    int4 i;
    i.x = *(int*)&p0; i.y = *(int*)&p1; i.z = *(int*)&p2; i.w = *(int*)&p3;
    return *(short8*)&i;
}
__device__ __forceinline__ short8 pack8s(float4 lo, float4 hi, float s) {
    lo.x *= s; lo.y *= s; lo.z *= s; lo.w *= s;
    hi.x *= s; hi.y *= s; hi.z *= s; hi.w *= s;
    return pack8(lo, hi);
}
// tanh(z) where v = 2*log2e*z is the prescaled MFMA result.
// Builtins (not asm) so MFMA->VALU hazards are compiler-handled (R3 lesson).
__device__ __forceinline__ float tanh_s(float v) {
    float e = __builtin_amdgcn_exp2f(v);          // 2^v = exp(2z)
    float r = __builtin_amdgcn_rcpf(e + 1.0f);
    return __builtin_fmaf(-2.0f, r, 1.0f);        // 1 - 2/(e+1)
}

__global__ __launch_bounds__(512, 2)
void rnn_fused(const float* __restrict__ x, const float* __restrict__ W_ih,
               const float* __restrict__ W_hh, const float* __restrict__ b_ih,
               const float* __restrict__ b_hh, const float* __restrict__ W_fc,
               const float* __restrict__ b_fc, float* __restrict__ out) {
    __shared__ __align__(16) short hbuf[2][16][256];   // h_t bf16, 16B-XOR swizzled
    __shared__ __align__(16) short xbuf[2][16][128];   // x_t bf16, 16B-XOR swizzled
    const int tid  = threadIdx.x;
    const int wave = tid >> 6, lane = tid & 63;
    const int l15  = lane & 15, quad = lane >> 4;
    const int b0   = blockIdx.x * 16;
    const int n0   = wave * 32;
    const int swz  = l15 & 7;

    // resident W_hh' fragments (prescaled)
    short8 wfrag[2][8];
#pragma unroll
    for (int mt = 0; mt < 2; ++mt)
#pragma unroll
        for (int kq = 0; kq < 8; ++kq) {
            const float* p = W_hh + (long)(n0 + mt * 16 + l15) * H_ + kq * 32 + quad * 8;
            wfrag[mt][kq] = pack8s(*(const float4*)p, *(const float4*)(p + 4), SCALE);
        }
    // resident W_ih' fragments (prescaled)
    short8 wih[2][4];
#pragma unroll
    for (int mt = 0; mt < 2; ++mt)
#pragma unroll
        for (int kq = 0; kq < 4; ++kq) {
            const float* p = W_ih + (long)(n0 + mt * 16 + l15) * I_ + kq * 32 + quad * 8;
            wih[mt][kq] = pack8s(*(const float4*)p, *(const float4*)(p + 4), SCALE);
        }
    // prescaled bias per output element: n = n0 + mt*16 + quad*4 + r
    floatx4 bias2[2];
#pragma unroll
    for (int mt = 0; mt < 2; ++mt)
#pragma unroll
        for (int r = 0; r < 4; ++r) {
            int n = n0 + mt * 16 + quad * 4 + r;
            bias2[mt][r] = SCALE * (b_ih[n] + b_hh[n]);
        }

    // zero hbuf[0] (h_0 = 0)
    {
        int* hz = (int*)&hbuf[0][0][0];
#pragma unroll
        for (int i = tid; i < 16 * 256 / 2; i += 512) hz[i] = 0;
    }

    // x staging: thread (sb=batch, sj=4-float chunk), 8B-granule swizzle sj^((sb&7)<<1)
    const int sb = tid >> 5, sj = tid & 31;
    const float* xsrc = x + (long)(b0 + sb) * T_ * I_ + sj * 4;
    const int xwoff = sb * 128 + ((sj ^ ((sb & 7) << 1)) << 2);
    {   // stage x_1 -> xbuf[1]
        float4 s1 = *(const float4*)(xsrc + I_);
        __hip_bfloat162 q0 = __float22bfloat162_rn(float2{s1.x, s1.y});
        __hip_bfloat162 q1 = __float22bfloat162_rn(float2{s1.z, s1.w});
        int2 sw; sw.x = *(int*)&q0; sw.y = *(int*)&q1;
        *(int2*)(&xbuf[1][0][0] + xwoff) = sw;
    }
    float4 xhA = *(const float4*)(xsrc + 2 * I_);   // x_2, written during step 0
    float4 xhB;

    // LDS read offsets (shorts)
    int roff[8];
#pragma unroll
    for (int kq = 0; kq < 8; ++kq)
        roff[kq] = l15 * 256 + (((quad + 4 * kq) ^ swz) << 3);
    int xroff[4];
#pragma unroll
    for (int kq = 0; kq < 4; ++kq)
        xroff[kq] = l15 * 128 + (((kq * 4 + quad) ^ swz) << 3);
    int woff[2];
#pragma unroll
    for (int mt = 0; mt < 2; ++mt) {
        int c = wave * 4 + 2 * mt + (quad >> 1);
        woff[mt] = l15 * 256 + ((c ^ swz) << 3) + (quad & 1) * 4;
    }

    // prolog: aA = bias' + W_ih'·x_0 (x_0 direct from global)
    floatx4 aA[2], aB[2];
    {
        short8 xf[4];
#pragma unroll
        for (int kq = 0; kq < 4; ++kq) {
            const float* p = x + (long)(b0 + l15) * T_ * I_ + kq * 32 + quad * 8;
            xf[kq] = pack8(*(const float4*)p, *(const float4*)(p + 4));
        }
#pragma unroll
        for (int mt = 0; mt < 2; ++mt) aA[mt] = bias2[mt];
#pragma unroll
        for (int kq = 0; kq < 4; ++kq)
#pragma unroll
            for (int mt = 0; mt < 2; ++mt)
                aA[mt] = __builtin_amdgcn_mfma_f32_16x16x32_bf16(
                    wih[mt][kq], xf[kq], aA[mt], 0, 0, 0);
    }
    __syncthreads();   // staging + zero visible before step 0

    const short* hb0r = &hbuf[0][0][0]; short* hb0w = &hbuf[0][0][0];
    const short* hb1r = &hbuf[1][0][0]; short* hb1w = &hbuf[1][0][0];
    const short* xb0r = &xbuf[0][0][0]; short* xb0w = &xbuf[0][0][0];
    const short* xb1r = &xbuf[1][0][0]; short* xb1w = &xbuf[1][0][0];

#define BAR() asm volatile("s_waitcnt lgkmcnt(0)\n\ts_barrier" ::: "memory")

#define STEP(HR, HW, XR, XW, ACUR, ANXT, XH, XN, TLD)                           \
    {                                                                           \
        /* 1. global x load for t+3: longest latency, fully off-path */         \
        XN = *(const float4*)(xsrc + (long)(TLD) * I_);                         \
        /* 2. h-fragment reads */                                               \
        short8 hfrag[8];                                                        \
        _Pragma("unroll")                                                       \
        for (int kq = 0; kq < 8; ++kq)                                          \
            hfrag[kq] = *(const short8*)((HR) + roff[kq]);                      \
        /* 3. 16 h-MFMAs as 4 independent depth-4 chains */                     \
        floatx4 aZ[2];                                                          \
        _Pragma("unroll")                                                       \
        for (int mt = 0; mt < 2; ++mt) aZ[mt] = (floatx4){0.f, 0.f, 0.f, 0.f};  \
        _Pragma("unroll")                                                       \
        for (int kq = 0; kq < 4; ++kq)                                          \
            _Pragma("unroll")                                                   \
            for (int mt = 0; mt < 2; ++mt) {                                    \
                ACUR[mt] = __builtin_amdgcn_mfma_f32_16x16x32_bf16(             \
                    wfrag[mt][kq], hfrag[kq], ACUR[mt], 0, 0, 0);               \
                aZ[mt] = __builtin_amdgcn_mfma_f32_16x16x32_bf16(               \
                    wfrag[mt][kq + 4], hfrag[kq + 4], aZ[mt], 0, 0, 0);         \
            }                                                                   \
        /* 4. x-frag reads + x stage write: land in the DS-idle compute phase */\
        short8 xfrag[4];                                                        \
        _Pragma("unroll")                                                       \
        for (int kq = 0; kq < 4; ++kq)                                          \
            xfrag[kq] = *(const short8*)((XR) + xroff[kq]);                     \
        {                                                                       \
            __hip_bfloat162 q0 = __float22bfloat162_rn(float2{XH.x, XH.y});     \
            __hip_bfloat162 q1 = __float22bfloat162_rn(float2{XH.z, XH.w});     \
            int2 sw; sw.x = *(int*)&q0; sw.y = *(int*)&q1;                      \
            *(int2*)((XW) + xwoff) = sw;                                        \
        }                                                                       \
        /* 5. merge + tanh + pack + h-write: the critical path to the barrier */\
        _Pragma("unroll")                                                       \
        for (int mt = 0; mt < 2; ++mt) {                                        \
            float r0 = tanh_s(ACUR[mt][0] + aZ[mt][0]);                         \
            float r1 = tanh_s(ACUR[mt][1] + aZ[mt][1]);                         \
            float r2 = tanh_s(ACUR[mt][2] + aZ[mt][2]);                         \
            float r3 = tanh_s(ACUR[mt][3] + aZ[mt][3]);                         \
            __hip_bfloat162 q01 = __float22bfloat162_rn(float2{r0, r1});        \
            __hip_bfloat162 q23 = __float22bfloat162_rn(float2{r2, r3});        \
            int2 wv; wv.x = *(int*)&q01; wv.y = *(int*)&q23;                    \
            *(int2*)((HW) + woff[mt]) = wv;                                     \
        }                                                                       \
        /* 6. x-MFMAs last: ANXT needed only after the next barrier; overlaps   \
              the epilogue VALU on the matrix pipe */                           \
        _Pragma("unroll")                                                       \
        for (int mt = 0; mt < 2; ++mt) ANXT[mt] = bias2[mt];                    \
        _Pragma("unroll")                                                       \
        for (int kq = 0; kq < 4; ++kq)                                          \
            _Pragma("unroll")                                                   \
            for (int mt = 0; mt < 2; ++mt)                                      \
                ANXT[mt] = __builtin_amdgcn_mfma_f32_16x16x32_bf16(             \
                    wih[mt][kq], xfrag[kq], ANXT[mt], 0, 0, 0);                 \
        BAR();                                                                  \
    }

#pragma unroll 1
    for (int t = 0; t < T_; t += 2) {
        const int tl0 = (t + 3 < T_) ? t + 3 : T_ - 1;
        const int tl1 = (t + 4 < T_) ? t + 4 : T_ - 1;
        STEP(hb0r, hb1w, xb1r, xb0w, aA, aB, xhA, xhB, tl0);   // even t
        STEP(hb1r, hb0w, xb0r, xb1w, aB, aA, xhB, xhA, tl1);   // odd t
    }
#undef STEP
#undef BAR

    // head: out[b] = sigmoid(b_fc + sum_n h_T[b][n] * W_fc[n]); h_T in hbuf[0] (swizzled)
    if (tid < 256) {
        const int bl = tid >> 4, seg = tid & 15;
        const int bswz = bl & 7;
        float p = 0.0f;
#pragma unroll
        for (int half = 0; half < 2; ++half) {
            const int c = 2 * seg + half;
            const short* hr = &hbuf[0][0][0] + bl * 256 + ((c ^ bswz) << 3);
#pragma unroll
            for (int i = 0; i < 8; ++i) {
                __hip_bfloat16 hv = *(const __hip_bfloat16*)(hr + i);
                p += __bfloat162float(hv) * W_fc[c * 8 + i];
            }
        }
#pragma unroll
        for (int off = 1; off < 16; off <<= 1) p += __shfl_xor(p, off);
        if (seg == 0) out[b0 + bl] = 1.0f / (1.0f + __expf(-(p + b_fc[0])));
    }
}

extern "C" void kernel_launch(void* const* d_in, const int* in_sizes, int n_in,
                              void* d_out, int out_size, void* d_ws, size_t ws_size,
                              hipStream_t stream) {
    const float* x    = (const float*)d_in[0];
    const float* W_ih = (const float*)d_in[1];
    const float* W_hh = (const float*)d_in[2];
    const float* b_ih = (const float*)d_in[3];
    const float* b_hh = (const float*)d_in[4];
    const float* W_fc = (const float*)d_in[5];
    const float* b_fc = (const float*)d_in[6];
    float* out = (float*)d_out;
    (void)d_ws; (void)ws_size;   // workspace not needed

    rnn_fused<<<B_ / 16, 512, 0, stream>>>(x, W_ih, W_hh, b_ih, b_hh, W_fc, b_fc, out);
}